// Round 1
// baseline (808.624 us; speedup 1.0000x reference)
//
#include <hip/hip_runtime.h>
#include <hip/hip_bf16.h>

// Problem constants
#define N_AG   32
#define B_SZ   16384
#define SD_    128
#define AD_    64
#define IDIM_  192
#define H_     256
#define HEADS_ 4
#define AT_    64
#define NO_    31   // N_AG-1 "others"

typedef __attribute__((ext_vector_type(8))) short bf16x8_t;
typedef __attribute__((ext_vector_type(4))) float f32x4_t;

__device__ inline unsigned short f2bfu(float f){
  union { __hip_bfloat16 h; unsigned short u; } cv;
  cv.h = __float2bfloat16(f);
  return cv.u;
}
__device__ inline float bfu2f(unsigned short u){
  union { float f; unsigned int i; } cv; cv.i = ((unsigned int)u) << 16; return cv.f;
}

// ---------------- prep: f32 (K,N) -> bf16 (N,K) transpose, batched -------------
__global__ __launch_bounds__(256) void k_transpose_bf16(
    const float* __restrict__ src, unsigned short* __restrict__ dst,
    int K, int N, long sstride, long dstride)
{
  long b = blockIdx.z;
  int idx = blockIdx.x * 256 + threadIdx.x;
  if (idx >= K * N) return;
  int n = idx / K, k = idx - n * K;
  dst[b * dstride + idx] = f2bfu(src[b * sstride + (long)k * N + n]);
}

// ---------------- prep: Mct[(e*256+h)][h'] = 0.125 * sum_d Wsel[e,h',d]*Wk[e,h,d]
__global__ __launch_bounds__(256) void k_mcomb(
    const float* __restrict__ Wsel, const float* __restrict__ Wk,
    unsigned short* __restrict__ Mct)
{
  int idx = blockIdx.x * 256 + threadIdx.x;   // idx = (e*256+h)*256 + hp
  int hp = idx & 255;
  int eh = idx >> 8;
  int e = eh >> 8;
  int h = eh & 255;
  const float* ws = Wsel + ((long)e * 256 + hp) * 64;
  const float* wk = Wk   + ((long)e * 256 + h ) * 64;
  float s = 0.f;
  #pragma unroll 8
  for (int d = 0; d < 64; d++) s += ws[d] * wk[d];
  Mct[idx] = f2bfu(0.125f * s);
}

// ---------------- generic MFMA GEMM: C = [lrelu](A @ B + bias) ------------------
// A: (M,K) f32 or bf16, row-major, lda. Bt: (N,K) bf16 row-major (B transposed).
// Tile 128x64, BK=32, 256 threads = 4 waves in 2x2, each wave 64x32 (4x2 frags).
template<bool AF32, bool LRELU, bool OUTF32>
__global__ __launch_bounds__(256) void k_gemm(
    const void* __restrict__ Ap, int lda, long strideA,
    const unsigned short* __restrict__ Bt, long strideB,
    const float* __restrict__ bias, long strideBias,
    void* __restrict__ Cp, int ldc, long strideC,
    int K)
{
  __shared__ __align__(16) unsigned short Alds[128][40];  // +8 pad: 2-way max
  __shared__ __align__(16) unsigned short Blds[64][40];

  const int tid = threadIdx.x;
  const int bm = blockIdx.x, bn = blockIdx.y, bz = blockIdx.z;
  const int w = tid >> 6, lane = tid & 63;
  const int wr = (w >> 1) * 64, wc = (w & 1) * 32;
  const int lr = lane & 15, lk = (lane >> 4) * 8;

  f32x4_t acc[4][2];
  #pragma unroll
  for (int i = 0; i < 4; i++)
    #pragma unroll
    for (int j = 0; j < 2; j++) acc[i][j] = (f32x4_t){0.f, 0.f, 0.f, 0.f};

  const unsigned short* Bb = Bt + bz * strideB + (long)(bn * 64) * K;

  for (int k0 = 0; k0 < K; k0 += 32) {
    // stage A tile (128x32)
    if (AF32) {
      const float* A = (const float*)Ap + bz * strideA + (long)(bm * 128) * lda + k0;
      #pragma unroll
      for (int i = 0; i < 4; i++) {
        int chunk = tid + i * 256;              // 1024 float4-chunks
        int m = chunk >> 3, kc = (chunk & 7) * 4;
        const float4 v = *reinterpret_cast<const float4*>(A + (long)m * lda + kc);
        ushort4 p;
        p.x = f2bfu(v.x); p.y = f2bfu(v.y); p.z = f2bfu(v.z); p.w = f2bfu(v.w);
        *reinterpret_cast<ushort4*>(&Alds[m][kc]) = p;
      }
    } else {
      const unsigned short* A = (const unsigned short*)Ap + bz * strideA + (long)(bm * 128) * lda + k0;
      #pragma unroll
      for (int i = 0; i < 4; i++) {
        int chunk = tid + i * 256;
        int m = chunk >> 3, kc = (chunk & 7) * 4;
        *reinterpret_cast<ushort4*>(&Alds[m][kc]) =
            *reinterpret_cast<const ushort4*>(A + (long)m * lda + kc);
      }
    }
    // stage B tile (64x32, n-major)
    #pragma unroll
    for (int i = 0; i < 2; i++) {
      int chunk = tid + i * 256;                // 512 chunks
      int n = chunk >> 3, kc = (chunk & 7) * 4;
      *reinterpret_cast<ushort4*>(&Blds[n][kc]) =
          *reinterpret_cast<const ushort4*>(Bb + (long)n * K + k0 + kc);
    }
    __syncthreads();

    bf16x8_t bfr0 = *reinterpret_cast<const bf16x8_t*>(&Blds[wc + lr][lk]);
    bf16x8_t bfr1 = *reinterpret_cast<const bf16x8_t*>(&Blds[wc + 16 + lr][lk]);
    #pragma unroll
    for (int mf = 0; mf < 4; mf++) {
      bf16x8_t afr = *reinterpret_cast<const bf16x8_t*>(&Alds[wr + mf * 16 + lr][lk]);
      acc[mf][0] = __builtin_amdgcn_mfma_f32_16x16x32_bf16(afr, bfr0, acc[mf][0], 0, 0, 0);
      acc[mf][1] = __builtin_amdgcn_mfma_f32_16x16x32_bf16(afr, bfr1, acc[mf][1], 0, 0, 0);
    }
    __syncthreads();
  }

  // epilogue: C/D layout col=lane&15, row=(lane>>4)*4+reg  [m89/m91 verified]
  const float* bp = bias ? bias + bz * strideBias : nullptr;
  #pragma unroll
  for (int nf = 0; nf < 2; nf++) {
    int col = bn * 64 + wc + nf * 16 + lr;
    float bvv = bp ? bp[col] : 0.f;
    #pragma unroll
    for (int mf = 0; mf < 4; mf++) {
      #pragma unroll
      for (int r = 0; r < 4; r++) {
        int row = bm * 128 + wr + mf * 16 + (lane >> 4) * 4 + r;
        float v = acc[mf][nf][r] + bvv;
        if (LRELU) v = v > 0.f ? v : 0.01f * v;
        if (OUTF32)
          ((float*)Cp)[bz * strideC + (long)row * ldc + col] = v;
        else
          ((unsigned short*)Cp)[bz * strideC + (long)row * ldc + col] = f2bfu(v);
      }
    }
  }
}

// ---------------- attention logits + softmax: w[b][e][n] ------------------------
__global__ __launch_bounds__(256) void k_attn(
    const unsigned short* __restrict__ others,  // [31][B][256] bf16
    const unsigned short* __restrict__ qb,      // [B][1024] bf16 (e*256+h)
    float* __restrict__ wout)                   // [B][4][31]
{
  __shared__ __align__(16) unsigned short oth[NO_][264];
  const int b = blockIdx.x;
  const int tid = threadIdx.x;
  #pragma unroll
  for (int i = 0; i < 8; i++) {
    int chunk = tid + i * 256;
    if (chunk < NO_ * 64) {
      int n = chunk >> 6, pos = (chunk & 63) * 4;
      *reinterpret_cast<ushort4*>(&oth[n][pos]) =
          *reinterpret_cast<const ushort4*>(others + ((long)n * B_SZ + b) * H_ + pos);
    }
  }
  const int e = tid >> 6, lane = tid & 63;
  ushort4 qv = *reinterpret_cast<const ushort4*>(qb + (long)b * 1024 + e * 256 + lane * 4);
  float q0 = bfu2f(qv.x), q1 = bfu2f(qv.y), q2 = bfu2f(qv.z), q3 = bfu2f(qv.w);
  __syncthreads();

  float myLogit = 0.f;
  for (int n = 0; n < NO_; n++) {
    ushort4 ov = *reinterpret_cast<const ushort4*>(&oth[n][lane * 4]);
    float v = q0 * bfu2f(ov.x) + q1 * bfu2f(ov.y) + q2 * bfu2f(ov.z) + q3 * bfu2f(ov.w);
    #pragma unroll
    for (int m = 32; m; m >>= 1) v += __shfl_xor(v, m);
    if (lane == n) myLogit = v;
  }
  float x = (lane < NO_) ? myLogit : -1e30f;
  float mx = x;
  #pragma unroll
  for (int m = 32; m; m >>= 1) mx = fmaxf(mx, __shfl_xor(mx, m));
  float p = (lane < NO_) ? expf(x - mx) : 0.f;
  float s = p;
  #pragma unroll
  for (int m = 32; m; m >>= 1) s += __shfl_xor(s, m);
  if (lane < NO_) wout[((long)b * HEADS_ + e) * NO_ + lane] = p / s;
}

// ---------------- weighted sum of vals -> critic cols [768,1024) ----------------
__global__ __launch_bounds__(256) void k_reduce(
    const unsigned short* __restrict__ vals,   // [31][B][256] bf16
    const float* __restrict__ wbuf,            // [B][4][31]
    unsigned short* __restrict__ critic)       // [B][1024] bf16
{
  __shared__ float wl[HEADS_ * NO_];
  const int b = blockIdx.x, tid = threadIdx.x;
  if (tid < HEADS_ * NO_) wl[tid] = wbuf[(long)b * HEADS_ * NO_ + tid];
  __syncthreads();
  const int e = tid >> 6;
  float acc = 0.f;
  for (int n = 0; n < NO_; n++)
    acc += wl[e * NO_ + n] * bfu2f(vals[((long)n * B_SZ + b) * H_ + tid]);
  critic[(long)b * 1024 + 768 + tid] = f2bfu(acc);
}

extern "C" void kernel_launch(void* const* d_in, const int* in_sizes, int n_in,
                              void* d_out, int out_size, void* d_ws, size_t ws_size,
                              hipStream_t stream)
{
  (void)in_sizes; (void)n_in; (void)out_size; (void)ws_size;
  const float* agent = (const float*)d_in[0];
  const float* state = (const float*)d_in[1];
  const float* mf    = (const float*)d_in[2];
  const float* mf2   = (const float*)d_in[3];
  const float* encW  = (const float*)d_in[4];
  const float* encb  = (const float*)d_in[5];
  const float* sW    = (const float*)d_in[6];
  const float* sb    = (const float*)d_in[7];
  const float* mfW   = (const float*)d_in[8];
  const float* mfb   = (const float*)d_in[9];
  const float* mf2W  = (const float*)d_in[10];
  const float* mf2b  = (const float*)d_in[11];
  const float* Wk    = (const float*)d_in[12];
  const float* Wsel  = (const float*)d_in[13];
  const float* Wv    = (const float*)d_in[14];
  const float* bv    = (const float*)d_in[15];
  const float* W1    = (const float*)d_in[16];
  const float* b1    = (const float*)d_in[17];
  const float* W2    = (const float*)d_in[18];
  const float* b2    = (const float*)d_in[19];
  float* out = (float*)d_out;

  char* ws = (char*)d_ws;
  size_t off = 0;
  auto alloc = [&](size_t bytes) -> char* {
    char* p = ws + off; off += (bytes + 255) & ~(size_t)255; return p;
  };
  unsigned short* others = (unsigned short*)alloc((size_t)NO_ * B_SZ * H_ * 2);   // 260 MB
  unsigned short* vals   = (unsigned short*)alloc((size_t)NO_ * B_SZ * H_ * 2);   // 260 MB
  unsigned short* qbuf   = (unsigned short*)alloc((size_t)B_SZ * 1024 * 2);       // 33 MB
  unsigned short* critic = (unsigned short*)alloc((size_t)B_SZ * 1024 * 2);       // 33 MB
  unsigned short* h1buf  = (unsigned short*)alloc((size_t)B_SZ * H_ * 2);         // 8 MB
  float*          wbuf   = (float*)alloc((size_t)B_SZ * HEADS_ * NO_ * 4);        // 8 MB
  unsigned short* encWt  = (unsigned short*)alloc((size_t)NO_ * H_ * IDIM_ * 2);
  unsigned short* Mct    = (unsigned short*)alloc((size_t)1024 * 256 * 2);
  unsigned short* WvT    = (unsigned short*)alloc((size_t)256 * 256 * 2);
  unsigned short* sWt    = (unsigned short*)alloc((size_t)256 * 128 * 2);
  unsigned short* mfWt   = (unsigned short*)alloc((size_t)256 * 64 * 2);
  unsigned short* mf2Wt  = (unsigned short*)alloc((size_t)256 * 64 * 2);
  unsigned short* W1t    = (unsigned short*)alloc((size_t)256 * 1024 * 2);
  unsigned short* W2t    = (unsigned short*)alloc((size_t)64 * 256 * 2);

  // ---- prep: transposed bf16 weights ----
  k_transpose_bf16<<<dim3(192, 1, NO_), 256, 0, stream>>>(
      encW + (size_t)IDIM_ * H_, encWt, IDIM_, H_, (long)IDIM_ * H_, (long)IDIM_ * H_);
  k_transpose_bf16<<<dim3(128, 1, 1), 256, 0, stream>>>(sW, sWt, SD_, H_, 0, 0);
  k_transpose_bf16<<<dim3(64, 1, 1), 256, 0, stream>>>(mfW, mfWt, AD_, H_, 0, 0);
  k_transpose_bf16<<<dim3(64, 1, 1), 256, 0, stream>>>(mf2W, mf2Wt, AD_, H_, 0, 0);
  k_transpose_bf16<<<dim3(1024, 1, 1), 256, 0, stream>>>(W1, W1t, 1024, H_, 0, 0);
  k_transpose_bf16<<<dim3(64, 1, 1), 256, 0, stream>>>(W2, W2t, H_, 64, 0, 0);
  k_transpose_bf16<<<dim3(64, 1, HEADS_), 256, 0, stream>>>(
      Wv, WvT, H_, AT_, (long)H_ * AT_, (long)H_ * AT_);
  k_mcomb<<<dim3(1024), 256, 0, stream>>>(Wsel, Wk, Mct);

  // ---- G1: others[n-1] = lrelu(agent[n] @ encW[n] + encb[n]), n=1..31 ----
  k_gemm<true, true, false><<<dim3(128, 4, NO_), 256, 0, stream>>>(
      agent + (size_t)B_SZ * IDIM_, IDIM_, (long)B_SZ * IDIM_,
      encWt, (long)H_ * IDIM_,
      encb + H_, H_,
      others, H_, (long)B_SZ * H_, IDIM_);

  // ---- G2: s_enc / mf_enc / mf2_enc into critic cols 0..767 ----
  k_gemm<true, true, false><<<dim3(128, 4, 1), 256, 0, stream>>>(
      state, SD_, 0, sWt, 0, sb, 0, critic, 1024, 0, SD_);
  k_gemm<true, true, false><<<dim3(128, 4, 1), 256, 0, stream>>>(
      mf, AD_, 0, mfWt, 0, mfb, 0, critic + 256, 1024, 0, AD_);
  k_gemm<true, true, false><<<dim3(128, 4, 1), 256, 0, stream>>>(
      mf2, AD_, 0, mf2Wt, 0, mf2b, 0, critic + 512, 1024, 0, AD_);

  // ---- G3: q[b][e*256+h] = s_enc @ Mct  (scale 1/8 folded into Mct) ----
  k_gemm<false, false, false><<<dim3(128, 16, 1), 256, 0, stream>>>(
      critic, 1024, 0, Mct, 0, nullptr, 0, qbuf, 1024, 0, 256);

  // ---- attention softmax weights ----
  k_attn<<<dim3(B_SZ), 256, 0, stream>>>(others, qbuf, wbuf);

  // ---- G4: vals = lrelu(others @ Wv_all + bv), M = 31*B ----
  k_gemm<false, true, false><<<dim3(3968, 4, 1), 256, 0, stream>>>(
      others, H_, 0, WvT, 0, bv, 0, vals, H_, 0, H_);

  // ---- weighted sum -> critic cols 768..1023 ----
  k_reduce<<<dim3(B_SZ), 256, 0, stream>>>(vals, wbuf, critic);

  // ---- G5: h1 = lrelu(critic @ W1 + b1) ----
  k_gemm<false, true, false><<<dim3(128, 4, 1), 256, 0, stream>>>(
      critic, 1024, 0, W1t, 0, b1, 0, h1buf, H_, 0, 1024);

  // ---- G6: out = h1 @ W2 + b2 (f32) ----
  k_gemm<false, false, true><<<dim3(128, 1, 1), 256, 0, stream>>>(
      h1buf, H_, 0, W2t, 0, b2, 0, out, 64, 0, 256);
}

// Round 2
// 609.552 us; speedup vs baseline: 1.3266x; 1.3266x over previous
//
#include <hip/hip_runtime.h>
#include <hip/hip_bf16.h>

// Problem constants
#define N_AG   32
#define B_SZ   16384
#define SD_    128
#define AD_    64
#define IDIM_  192
#define H_     256
#define HEADS_ 4
#define AT_    64
#define NO_    31   // N_AG-1 "others"

typedef __attribute__((ext_vector_type(8))) short bf16x8_t;
typedef __attribute__((ext_vector_type(4))) float f32x4_t;

__device__ inline unsigned short f2bfu(float f){
  union { __hip_bfloat16 h; unsigned short u; } cv;
  cv.h = __float2bfloat16(f);
  return cv.u;
}
__device__ inline float bfu2f(unsigned short u){
  union { float f; unsigned int i; } cv; cv.i = ((unsigned int)u) << 16; return cv.f;
}

// async global->LDS 16B (dest = wave-uniform base + lane*16)
__device__ inline void gll16(const unsigned short* g, unsigned short* l) {
  __builtin_amdgcn_global_load_lds(
      (const __attribute__((address_space(1))) unsigned int*)g,
      (__attribute__((address_space(3))) unsigned int*)l, 16, 0, 0);
}

// swizzled LDS index (ushort units) for a [rows][64] bf16 tile (128B rows):
// 16B slot s of row r lives at slot s^(r&7)
__device__ inline int swz_idx(int row, int slot) {
  return row * 64 + (((slot ^ (row & 7)) & 7) << 3);
}

// ---------------- prep: f32 (K,N) -> bf16 (N,K) transpose, batched -------------
__global__ __launch_bounds__(256) void k_transpose_bf16(
    const float* __restrict__ src, unsigned short* __restrict__ dst,
    int K, int N, long sstride, long dstride)
{
  long b = blockIdx.z;
  int idx = blockIdx.x * 256 + threadIdx.x;
  if (idx >= K * N) return;
  int n = idx / K, k = idx - n * K;
  dst[b * dstride + idx] = f2bfu(src[b * sstride + (long)k * N + n]);
}

// ---------------- prep: Mct[(e*256+h)][h'] = 0.125 * sum_d Wsel[e,h',d]*Wk[e,h,d]
__global__ __launch_bounds__(256) void k_mcomb(
    const float* __restrict__ Wsel, const float* __restrict__ Wk,
    unsigned short* __restrict__ Mct)
{
  int idx = blockIdx.x * 256 + threadIdx.x;   // idx = (e*256+h)*256 + hp
  int hp = idx & 255;
  int eh = idx >> 8;
  int e = eh >> 8;
  int h = eh & 255;
  const float* ws = Wsel + ((long)e * 256 + hp) * 64;
  const float* wk = Wk   + ((long)e * 256 + h ) * 64;
  float s = 0.f;
  #pragma unroll 8
  for (int d = 0; d < 64; d++) s += ws[d] * wk[d];
  Mct[idx] = f2bfu(0.125f * s);
}

// =====================================================================
// Wide GEMM: tile 64(M) x 256(N), BK=64, 512 threads = 8 waves (2x4).
// A: (M,K) f32 or bf16 row-major. Bt: (N,K) bf16 row-major. N-tile fixed 256.
// LDS XOR-swizzled (st-style): global source pre-swizzled for gll16 (rule 21).
// =====================================================================
template<bool AF32, bool LRELU, bool OUTF32>
__global__ __launch_bounds__(512) void k_gemm2(
    const void* __restrict__ Ap, int lda, long strideA,
    const unsigned short* __restrict__ Bt, long strideB,
    const float* __restrict__ bias, long strideBias,
    void* __restrict__ Cp, int ldc, long strideC,
    int K)
{
  __shared__ __align__(16) unsigned short Alds[64 * 64];    // 8 KB
  __shared__ __align__(16) unsigned short Blds[256 * 64];   // 32 KB

  const int tid = threadIdx.x;
  const int lane = tid & 63, w = tid >> 6;
  const int wr = w >> 2, wc = w & 3;          // wave grid 2 x 4 -> wave tile 32x64
  const int lr = lane & 15, lg = lane >> 4;
  const int bm = blockIdx.x, bn = blockIdx.y, bz = blockIdx.z;

  f32x4_t acc[2][4];
  #pragma unroll
  for (int i = 0; i < 2; i++)
    #pragma unroll
    for (int j = 0; j < 4; j++) acc[i][j] = (f32x4_t){0.f, 0.f, 0.f, 0.f};

  const unsigned short* Bb = Bt + bz * strideB + (long)(bn * 256) * K;

  for (int k0 = 0; k0 < K; k0 += 64) {
    // ---- stage B tile (256 x 64 bf16 = 32 KB), 4 x gll16 per thread ----
    #pragma unroll
    for (int i = 0; i < 4; i++) {
      int c = i * 512 + tid;
      int n = c >> 3, sl = c & 7;
      gll16(Bb + (long)n * K + k0 + (((sl ^ (n & 7)) & 7) << 3), Blds + c * 8);
    }
    // ---- stage A tile (64 x 64) ----
    if (AF32) {
      const float* Af = (const float*)Ap + bz * strideA + (long)(bm * 64) * lda + k0;
      #pragma unroll
      for (int i = 0; i < 2; i++) {
        int c = i * 512 + tid;                  // 1024 float4 chunks
        int row = c >> 4, q = c & 15;
        float4 v = *reinterpret_cast<const float4*>(Af + (long)row * lda + q * 4);
        ushort4 u;
        u.x = f2bfu(v.x); u.y = f2bfu(v.y); u.z = f2bfu(v.z); u.w = f2bfu(v.w);
        int di = row * 64 + ((((q >> 1) ^ (row & 7)) & 7) << 3) + ((q & 1) << 2);
        *reinterpret_cast<ushort4*>(&Alds[di]) = u;
      }
    } else {
      const unsigned short* Ab = (const unsigned short*)Ap + bz * strideA + (long)(bm * 64) * lda + k0;
      int c = tid;
      int row = c >> 3, sl = c & 7;
      gll16(Ab + (long)row * lda + (((sl ^ (row & 7)) & 7) << 3), Alds + c * 8);
    }
    __syncthreads();

    bf16x8_t af[2][2], bf[4][2];
    #pragma unroll
    for (int mf = 0; mf < 2; mf++)
      #pragma unroll
      for (int kk = 0; kk < 2; kk++) {
        int row = wr * 32 + mf * 16 + lr;
        af[mf][kk] = *reinterpret_cast<const bf16x8_t*>(&Alds[swz_idx(row, kk * 4 + lg)]);
      }
    #pragma unroll
    for (int nf = 0; nf < 4; nf++)
      #pragma unroll
      for (int kk = 0; kk < 2; kk++) {
        int n = wc * 64 + nf * 16 + lr;
        bf[nf][kk] = *reinterpret_cast<const bf16x8_t*>(&Blds[swz_idx(n, kk * 4 + lg)]);
      }
    #pragma unroll
    for (int kk = 0; kk < 2; kk++)
      #pragma unroll
      for (int mf = 0; mf < 2; mf++)
        #pragma unroll
        for (int nf = 0; nf < 4; nf++)
          acc[mf][nf] = __builtin_amdgcn_mfma_f32_16x16x32_bf16(af[mf][kk], bf[nf][kk], acc[mf][nf], 0, 0, 0);
    __syncthreads();
  }

  // epilogue: C/D layout col=lane&15, row=(lane>>4)*4+reg
  const float* bp = bias ? bias + bz * strideBias : nullptr;
  #pragma unroll
  for (int nf = 0; nf < 4; nf++) {
    int col = bn * 256 + wc * 64 + nf * 16 + lr;
    float bvv = bp ? bp[col] : 0.f;
    #pragma unroll
    for (int mf = 0; mf < 2; mf++) {
      #pragma unroll
      for (int r = 0; r < 4; r++) {
        int row = bm * 64 + wr * 32 + mf * 16 + lg * 4 + r;
        float v = acc[mf][nf][r] + bvv;
        if (LRELU) v = v > 0.f ? v : 0.01f * v;
        if (OUTF32)
          ((float*)Cp)[bz * strideC + (long)row * ldc + col] = v;
        else
          ((unsigned short*)Cp)[bz * strideC + (long)row * ldc + col] = f2bfu(v);
      }
    }
  }
}

// =====================================================================
// Fused vals-projection + weighted reduce:
// critic[b][768+e*64+d] = sum_n w[b,e,n] * lrelu(others[b,n,:]@Wv[e,:,d] + bv[e,d])
// tile: 64 b-rows x 256 cols, loop n serially; BK=64 staged per step.
// =====================================================================
__global__ __launch_bounds__(512) void k_valsred(
    const unsigned short* __restrict__ others,  // [B][31][256] bf16
    const unsigned short* __restrict__ WvT,     // [256][256] bf16 (col=e*64+d, k=h)
    const float* __restrict__ wbuf,             // [B][124]  (e*31+n)
    const float* __restrict__ bv,               // [4][64]
    unsigned short* __restrict__ critic)        // [B][1024]
{
  __shared__ __align__(16) unsigned short Alds[64 * 64];
  __shared__ __align__(16) unsigned short Blds[256 * 64];
  __shared__ float wlds[2][256];                // [dbuf][64 rows][4 e]

  const int tid = threadIdx.x;
  const int lane = tid & 63, w = tid >> 6;
  const int wr = w >> 2, wc = w & 3;
  const int lr = lane & 15, lg = lane >> 4;
  const int bm = blockIdx.x;

  f32x4_t outa[2][4];
  #pragma unroll
  for (int i = 0; i < 2; i++)
    #pragma unroll
    for (int j = 0; j < 4; j++) outa[i][j] = (f32x4_t){0.f, 0.f, 0.f, 0.f};

  float bvv[4];
  #pragma unroll
  for (int nf = 0; nf < 4; nf++) bvv[nf] = bv[wc * 64 + nf * 16 + lr];

  for (int n = 0; n < NO_; n++) {
    if (tid < 256)
      wlds[n & 1][tid] = wbuf[((long)(bm * 64) + (tid >> 2)) * 124 + (tid & 3) * 31 + n];

    f32x4_t va[2][4];
    #pragma unroll
    for (int i = 0; i < 2; i++)
      #pragma unroll
      for (int j = 0; j < 4; j++) va[i][j] = (f32x4_t){0.f, 0.f, 0.f, 0.f};

    for (int k0 = 0; k0 < 256; k0 += 64) {
      #pragma unroll
      for (int i = 0; i < 4; i++) {
        int c = i * 512 + tid;
        int nr = c >> 3, sl = c & 7;
        gll16(WvT + (long)nr * 256 + k0 + (((sl ^ (nr & 7)) & 7) << 3), Blds + c * 8);
      }
      {
        int c = tid;
        int row = c >> 3, sl = c & 7;
        gll16(others + ((long)(bm * 64 + row) * NO_ + n) * 256 + k0 + (((sl ^ (row & 7)) & 7) << 3),
              Alds + c * 8);
      }
      __syncthreads();

      bf16x8_t af[2][2], bfv[4][2];
      #pragma unroll
      for (int mf = 0; mf < 2; mf++)
        #pragma unroll
        for (int kk = 0; kk < 2; kk++) {
          int row = wr * 32 + mf * 16 + lr;
          af[mf][kk] = *reinterpret_cast<const bf16x8_t*>(&Alds[swz_idx(row, kk * 4 + lg)]);
        }
      #pragma unroll
      for (int nf = 0; nf < 4; nf++)
        #pragma unroll
        for (int kk = 0; kk < 2; kk++) {
          int nn = wc * 64 + nf * 16 + lr;
          bfv[nf][kk] = *reinterpret_cast<const bf16x8_t*>(&Blds[swz_idx(nn, kk * 4 + lg)]);
        }
      #pragma unroll
      for (int kk = 0; kk < 2; kk++)
        #pragma unroll
        for (int mf = 0; mf < 2; mf++)
          #pragma unroll
          for (int nf = 0; nf < 4; nf++)
            va[mf][nf] = __builtin_amdgcn_mfma_f32_16x16x32_bf16(af[mf][kk], bfv[nf][kk], va[mf][nf], 0, 0, 0);
      __syncthreads();
    }

    // fold lrelu + weight into running accumulator
    #pragma unroll
    for (int mf = 0; mf < 2; mf++) {
      #pragma unroll
      for (int r = 0; r < 4; r++) {
        float wv = wlds[n & 1][(wr * 32 + mf * 16 + lg * 4 + r) * 4 + wc];
        #pragma unroll
        for (int nf = 0; nf < 4; nf++) {
          float v = va[mf][nf][r] + bvv[nf];
          v = v > 0.f ? v : 0.01f * v;
          outa[mf][nf][r] += wv * v;
        }
      }
    }
  }

  #pragma unroll
  for (int nf = 0; nf < 4; nf++) {
    int col = 768 + wc * 64 + nf * 16 + lr;
    #pragma unroll
    for (int mf = 0; mf < 2; mf++)
      #pragma unroll
      for (int r = 0; r < 4; r++) {
        int row = bm * 64 + wr * 32 + mf * 16 + lg * 4 + r;
        critic[(long)row * 1024 + col] = f2bfu(outa[mf][nf][r]);
      }
  }
}

// ---------------- attention logits + softmax: w[b][e*31+n] ------------------------
__global__ __launch_bounds__(256) void k_attn(
    const unsigned short* __restrict__ others,  // [B][31][256] bf16
    const unsigned short* __restrict__ qb,      // [B][1024] bf16 (e*256+h)
    float* __restrict__ wout)                   // [B][124]
{
  __shared__ __align__(16) unsigned short oth[NO_][264];
  const int b = blockIdx.x;
  const int tid = threadIdx.x;
  const unsigned short* src = others + (long)b * NO_ * 256;
  #pragma unroll
  for (int i = 0; i < 8; i++) {
    int c = tid + i * 256;
    if (c < NO_ * 64) {
      int n = c >> 6, pos = (c & 63) * 4;
      *reinterpret_cast<ushort4*>(&oth[n][pos]) =
          *reinterpret_cast<const ushort4*>(src + c * 4);
    }
  }
  const int e = tid >> 6, lane = tid & 63;
  ushort4 qv = *reinterpret_cast<const ushort4*>(qb + (long)b * 1024 + e * 256 + lane * 4);
  float q0 = bfu2f(qv.x), q1 = bfu2f(qv.y), q2 = bfu2f(qv.z), q3 = bfu2f(qv.w);
  __syncthreads();

  float myLogit = 0.f;
  for (int n = 0; n < NO_; n++) {
    ushort4 ov = *reinterpret_cast<const ushort4*>(&oth[n][lane * 4]);
    float v = q0 * bfu2f(ov.x) + q1 * bfu2f(ov.y) + q2 * bfu2f(ov.z) + q3 * bfu2f(ov.w);
    #pragma unroll
    for (int m = 32; m; m >>= 1) v += __shfl_xor(v, m);
    if (lane == n) myLogit = v;
  }
  float x = (lane < NO_) ? myLogit : -1e30f;
  float mx = x;
  #pragma unroll
  for (int m = 32; m; m >>= 1) mx = fmaxf(mx, __shfl_xor(mx, m));
  float p = (lane < NO_) ? expf(x - mx) : 0.f;
  float s = p;
  #pragma unroll
  for (int m = 32; m; m >>= 1) s += __shfl_xor(s, m);
  if (lane < NO_) wout[(long)b * 124 + e * 31 + lane] = p / s;
}

// ---------------- small legacy GEMM (used for G6 only: N=64 tile) ---------------
template<bool AF32, bool LRELU, bool OUTF32>
__global__ __launch_bounds__(256) void k_gemm(
    const void* __restrict__ Ap, int lda, long strideA,
    const unsigned short* __restrict__ Bt, long strideB,
    const float* __restrict__ bias, long strideBias,
    void* __restrict__ Cp, int ldc, long strideC,
    int K)
{
  __shared__ __align__(16) unsigned short Alds[128][40];
  __shared__ __align__(16) unsigned short Blds[64][40];

  const int tid = threadIdx.x;
  const int bm = blockIdx.x, bn = blockIdx.y, bz = blockIdx.z;
  const int w = tid >> 6, lane = tid & 63;
  const int wr = (w >> 1) * 64, wc = (w & 1) * 32;
  const int lr = lane & 15, lk = (lane >> 4) * 8;

  f32x4_t acc[4][2];
  #pragma unroll
  for (int i = 0; i < 4; i++)
    #pragma unroll
    for (int j = 0; j < 2; j++) acc[i][j] = (f32x4_t){0.f, 0.f, 0.f, 0.f};

  const unsigned short* Bb = Bt + bz * strideB + (long)(bn * 64) * K;

  for (int k0 = 0; k0 < K; k0 += 32) {
    if (AF32) {
      const float* A = (const float*)Ap + bz * strideA + (long)(bm * 128) * lda + k0;
      #pragma unroll
      for (int i = 0; i < 4; i++) {
        int chunk = tid + i * 256;
        int m = chunk >> 3, kc = (chunk & 7) * 4;
        const float4 v = *reinterpret_cast<const float4*>(A + (long)m * lda + kc);
        ushort4 p;
        p.x = f2bfu(v.x); p.y = f2bfu(v.y); p.z = f2bfu(v.z); p.w = f2bfu(v.w);
        *reinterpret_cast<ushort4*>(&Alds[m][kc]) = p;
      }
    } else {
      const unsigned short* A = (const unsigned short*)Ap + bz * strideA + (long)(bm * 128) * lda + k0;
      #pragma unroll
      for (int i = 0; i < 4; i++) {
        int chunk = tid + i * 256;
        int m = chunk >> 3, kc = (chunk & 7) * 4;
        *reinterpret_cast<ushort4*>(&Alds[m][kc]) =
            *reinterpret_cast<const ushort4*>(A + (long)m * lda + kc);
      }
    }
    #pragma unroll
    for (int i = 0; i < 2; i++) {
      int chunk = tid + i * 256;
      int n = chunk >> 3, kc = (chunk & 7) * 4;
      *reinterpret_cast<ushort4*>(&Blds[n][kc]) =
          *reinterpret_cast<const ushort4*>(Bb + (long)n * K + k0 + kc);
    }
    __syncthreads();

    bf16x8_t bfr0 = *reinterpret_cast<const bf16x8_t*>(&Blds[wc + lr][lk]);
    bf16x8_t bfr1 = *reinterpret_cast<const bf16x8_t*>(&Blds[wc + 16 + lr][lk]);
    #pragma unroll
    for (int mf = 0; mf < 4; mf++) {
      bf16x8_t afr = *reinterpret_cast<const bf16x8_t*>(&Alds[wr + mf * 16 + lr][lk]);
      acc[mf][0] = __builtin_amdgcn_mfma_f32_16x16x32_bf16(afr, bfr0, acc[mf][0], 0, 0, 0);
      acc[mf][1] = __builtin_amdgcn_mfma_f32_16x16x32_bf16(afr, bfr1, acc[mf][1], 0, 0, 0);
    }
    __syncthreads();
  }

  const float* bp = bias ? bias + bz * strideBias : nullptr;
  #pragma unroll
  for (int nf = 0; nf < 2; nf++) {
    int col = bn * 64 + wc + nf * 16 + lr;
    float bvv = bp ? bp[col] : 0.f;
    #pragma unroll
    for (int mf = 0; mf < 4; mf++) {
      #pragma unroll
      for (int r = 0; r < 4; r++) {
        int row = bm * 128 + wr + mf * 16 + (lane >> 4) * 4 + r;
        float v = acc[mf][nf][r] + bvv;
        if (LRELU) v = v > 0.f ? v : 0.01f * v;
        if (OUTF32)
          ((float*)Cp)[bz * strideC + (long)row * ldc + col] = v;
        else
          ((unsigned short*)Cp)[bz * strideC + (long)row * ldc + col] = f2bfu(v);
      }
    }
  }
}

extern "C" void kernel_launch(void* const* d_in, const int* in_sizes, int n_in,
                              void* d_out, int out_size, void* d_ws, size_t ws_size,
                              hipStream_t stream)
{
  (void)in_sizes; (void)n_in; (void)out_size; (void)ws_size;
  const float* agent = (const float*)d_in[0];
  const float* state = (const float*)d_in[1];
  const float* mf    = (const float*)d_in[2];
  const float* mf2   = (const float*)d_in[3];
  const float* encW  = (const float*)d_in[4];
  const float* encb  = (const float*)d_in[5];
  const float* sW    = (const float*)d_in[6];
  const float* sb    = (const float*)d_in[7];
  const float* mfW   = (const float*)d_in[8];
  const float* mfb   = (const float*)d_in[9];
  const float* mf2W  = (const float*)d_in[10];
  const float* mf2b  = (const float*)d_in[11];
  const float* Wk    = (const float*)d_in[12];
  const float* Wsel  = (const float*)d_in[13];
  const float* Wv    = (const float*)d_in[14];
  const float* bv    = (const float*)d_in[15];
  const float* W1    = (const float*)d_in[16];
  const float* b1    = (const float*)d_in[17];
  const float* W2    = (const float*)d_in[18];
  const float* b2    = (const float*)d_in[19];
  float* out = (float*)d_out;

  char* ws = (char*)d_ws;
  size_t off = 0;
  auto alloc = [&](size_t bytes) -> char* {
    char* p = ws + off; off += (bytes + 255) & ~(size_t)255; return p;
  };
  unsigned short* others = (unsigned short*)alloc((size_t)B_SZ * NO_ * H_ * 2);   // [b][31][256]
  unsigned short* qbuf   = (unsigned short*)alloc((size_t)B_SZ * 1024 * 2);
  unsigned short* critic = (unsigned short*)alloc((size_t)B_SZ * 1024 * 2);
  unsigned short* h1buf  = (unsigned short*)alloc((size_t)B_SZ * H_ * 2);
  float*          wbuf   = (float*)alloc((size_t)B_SZ * HEADS_ * NO_ * 4);        // [b][124]
  unsigned short* encWt  = (unsigned short*)alloc((size_t)NO_ * H_ * IDIM_ * 2);
  unsigned short* Mct    = (unsigned short*)alloc((size_t)1024 * 256 * 2);
  unsigned short* WvT    = (unsigned short*)alloc((size_t)256 * 256 * 2);
  unsigned short* sWt    = (unsigned short*)alloc((size_t)256 * 128 * 2);
  unsigned short* mfWt   = (unsigned short*)alloc((size_t)256 * 64 * 2);
  unsigned short* mf2Wt  = (unsigned short*)alloc((size_t)256 * 64 * 2);
  unsigned short* W1t    = (unsigned short*)alloc((size_t)256 * 1024 * 2);
  unsigned short* W2t    = (unsigned short*)alloc((size_t)64 * 256 * 2);

  // ---- prep: transposed bf16 weights ----
  k_transpose_bf16<<<dim3(192, 1, NO_), 256, 0, stream>>>(
      encW + (size_t)IDIM_ * H_, encWt, IDIM_, H_, (long)IDIM_ * H_, (long)IDIM_ * H_);
  k_transpose_bf16<<<dim3(128, 1, 1), 256, 0, stream>>>(sW, sWt, SD_, H_, 0, 0);
  k_transpose_bf16<<<dim3(64, 1, 1), 256, 0, stream>>>(mfW, mfWt, AD_, H_, 0, 0);
  k_transpose_bf16<<<dim3(64, 1, 1), 256, 0, stream>>>(mf2W, mf2Wt, AD_, H_, 0, 0);
  k_transpose_bf16<<<dim3(1024, 1, 1), 256, 0, stream>>>(W1, W1t, 1024, H_, 0, 0);
  k_transpose_bf16<<<dim3(64, 1, 1), 256, 0, stream>>>(W2, W2t, H_, 64, 0, 0);
  k_transpose_bf16<<<dim3(64, 1, HEADS_), 256, 0, stream>>>(
      Wv, WvT, H_, AT_, (long)H_ * AT_, (long)H_ * AT_);
  k_mcomb<<<dim3(1024), 256, 0, stream>>>(Wsel, Wk, Mct);

  // ---- G1: others[b][n][:] = lrelu(agent[n+1] @ encW[n+1] + encb[n+1]) ----
  k_gemm2<true, true, false><<<dim3(256, 1, NO_), 512, 0, stream>>>(
      agent + (size_t)B_SZ * IDIM_, IDIM_, (long)B_SZ * IDIM_,
      encWt, (long)H_ * IDIM_,
      encb + H_, H_,
      others, NO_ * H_, H_ /*strideC per z*/, IDIM_);

  // ---- G2: s_enc / mf_enc / mf2_enc into critic cols 0..767 ----
  k_gemm2<true, true, false><<<dim3(256, 1, 1), 512, 0, stream>>>(
      state, SD_, 0, sWt, 0, sb, 0, critic, 1024, 0, SD_);
  k_gemm2<true, true, false><<<dim3(256, 1, 1), 512, 0, stream>>>(
      mf, AD_, 0, mfWt, 0, mfb, 0, critic + 256, 1024, 0, AD_);
  k_gemm2<true, true, false><<<dim3(256, 1, 1), 512, 0, stream>>>(
      mf2, AD_, 0, mf2Wt, 0, mf2b, 0, critic + 512, 1024, 0, AD_);

  // ---- G3: q = s_enc @ Mct (scale folded), N=1024 ----
  k_gemm2<false, false, false><<<dim3(256, 4, 1), 512, 0, stream>>>(
      critic, 1024, 0, Mct, 0, nullptr, 0, qbuf, 1024, 0, 256);

  // ---- attention softmax weights ----
  k_attn<<<dim3(B_SZ), 256, 0, stream>>>(others, qbuf, wbuf);

  // ---- fused vals + weighted reduce -> critic cols 768..1023 ----
  k_valsred<<<dim3(256), 512, 0, stream>>>(others, WvT, wbuf, bv, critic);

  // ---- G5: h1 = lrelu(critic @ W1 + b1) ----
  k_gemm2<false, true, false><<<dim3(256, 1, 1), 512, 0, stream>>>(
      critic, 1024, 0, W1t, 0, b1, 0, h1buf, H_, 0, 1024);

  // ---- G6: out = h1 @ W2 + b2 (f32) ----
  k_gemm<false, false, true><<<dim3(128, 1, 1), 256, 0, stream>>>(
      h1buf, H_, 0, W2t, 0, b2, 0, out, 64, 0, 256);
}